// Round 1
// baseline (5626.928 us; speedup 1.0000x reference)
//
#include <hip/hip_runtime.h>
#include <math.h>

#define HEADS 2
#define CH    128          // per-head channels
#define HC    256          // HEADS*CH
#define NEG   0.2f         // leaky_relu slope

// ---------------------------------------------------------------------------
// GEMM: C[N,HC] = A[N,K] @ W[K,HC]   (fp32, 64x64 tile, BK=32, 256 thr, 4x4/thr)
// ---------------------------------------------------------------------------
__global__ __launch_bounds__(256)
void gemm_kernel(const float* __restrict__ A, const float* __restrict__ W,
                 float* __restrict__ C, int N, int K) {
    __shared__ float As[32][68];   // [k][m], padded: 68*4B stride keeps 16B align
    __shared__ float Ws[32][68];   // [k][n]
    const int t    = threadIdx.x;
    const int row0 = blockIdx.x * 64;
    const int col0 = blockIdx.y * 64;
    const int tm   = t >> 4;       // 0..15
    const int tn   = t & 15;       // 0..15

    float acc[4][4] = {};

    for (int kk = 0; kk < K; kk += 32) {
        // stage A tile (64 rows x 32 k), transposed into As[k][m]
        {
            const int r  = t >> 3;          // 0..31
            const int c4 = (t & 7) * 4;     // 0..28
            #pragma unroll
            for (int half = 0; half < 2; ++half) {
                const int rr   = r + half * 32;
                const int grow = row0 + rr;
                float4 v = make_float4(0.f, 0.f, 0.f, 0.f);
                if (grow < N)
                    v = *reinterpret_cast<const float4*>(&A[(size_t)grow * K + kk + c4]);
                As[c4 + 0][rr] = v.x; As[c4 + 1][rr] = v.y;
                As[c4 + 2][rr] = v.z; As[c4 + 3][rr] = v.w;
            }
        }
        // stage W tile (32 k x 64 cols)
        {
            const int r  = t >> 4;          // 0..15
            const int c4 = (t & 15) * 4;    // 0..60
            #pragma unroll
            for (int half = 0; half < 2; ++half) {
                const int rr = r + half * 16;   // 0..31
                float4 v = *reinterpret_cast<const float4*>(
                    &W[(size_t)(kk + rr) * HC + col0 + c4]);
                *reinterpret_cast<float4*>(&Ws[rr][c4]) = v;
            }
        }
        __syncthreads();

        #pragma unroll 8
        for (int k = 0; k < 32; ++k) {
            float4 av = *reinterpret_cast<const float4*>(&As[k][tm * 4]);
            float4 bv = *reinterpret_cast<const float4*>(&Ws[k][tn * 4]);
            float a[4] = {av.x, av.y, av.z, av.w};
            float b[4] = {bv.x, bv.y, bv.z, bv.w};
            #pragma unroll
            for (int i = 0; i < 4; ++i)
                #pragma unroll
                for (int j = 0; j < 4; ++j)
                    acc[i][j] = fmaf(a[i], b[j], acc[i][j]);
        }
        __syncthreads();
    }

    #pragma unroll
    for (int i = 0; i < 4; ++i) {
        const int grow = row0 + tm * 4 + i;
        if (grow < N) {
            float4 v = make_float4(acc[i][0], acc[i][1], acc[i][2], acc[i][3]);
            *reinterpret_cast<float4*>(&C[(size_t)grow * HC + col0 + tn * 4]) = v;
        }
    }
}

// ---------------------------------------------------------------------------
// alpha: as[n,h] = dot(xW[n,h,:], a_src[h,:]);  ad likewise. one wave / node
// ---------------------------------------------------------------------------
__global__ __launch_bounds__(256)
void alpha_kernel(const float* __restrict__ xW, const float* __restrict__ a_src,
                  const float* __restrict__ a_dst, float* __restrict__ as_out,
                  float* __restrict__ ad_out, int N) {
    const int wid  = (blockIdx.x * 256 + threadIdx.x) >> 6;
    const int lane = threadIdx.x & 63;
    if (wid >= N) return;
    const int h  = lane >> 5;           // lanes 0..31 -> head 0, 32..63 -> head 1
    const int c0 = (lane & 31) * 4;
    const float4 v  = *reinterpret_cast<const float4*>(&xW[(size_t)wid * HC + lane * 4]);
    const float4 s4 = *reinterpret_cast<const float4*>(&a_src[h * CH + c0]);
    const float4 d4 = *reinterpret_cast<const float4*>(&a_dst[h * CH + c0]);
    float s = v.x * s4.x + v.y * s4.y + v.z * s4.z + v.w * s4.w;
    float d = v.x * d4.x + v.y * d4.y + v.z * d4.z + v.w * d4.w;
    #pragma unroll
    for (int m = 1; m <= 16; m <<= 1) {
        s += __shfl_xor(s, m);
        d += __shfl_xor(d, m);
    }
    if ((lane & 31) == 0) {
        as_out[wid * 2 + h] = s;
        ad_out[wid * 2 + h] = d;
    }
}

// ---------------------------------------------------------------------------
// edge scatter: one wave per edge j->i.
//   w = exp(leaky_relu(as[j]+ad[i]))  (max-shift skipped; cancels in the ratio)
//   denom[i,h] += w ;  acc[i,:] += w * xW[j,:]
// ---------------------------------------------------------------------------
__global__ __launch_bounds__(256)
void edge_kernel(const int* __restrict__ src, const int* __restrict__ dst,
                 const float* __restrict__ xW, const float* __restrict__ as_,
                 const float* __restrict__ ad_, float* __restrict__ acc,
                 float* __restrict__ denom, int E) {
    const int wid  = (blockIdx.x * 256 + threadIdx.x) >> 6;
    const int lane = threadIdx.x & 63;
    if (wid >= E) return;
    const int j = src[wid];
    const int i = dst[wid];
    const int h = lane >> 5;
    float e = as_[j * 2 + h] + ad_[i * 2 + h];
    e = e > 0.f ? e : NEG * e;
    const float w = expf(e);
    if ((lane & 31) == 0) unsafeAtomicAdd(&denom[i * 2 + h], w);
    const float4 v = *reinterpret_cast<const float4*>(&xW[(size_t)j * HC + lane * 4]);
    float* p = &acc[(size_t)i * HC + lane * 4];
    unsafeAtomicAdd(p + 0, w * v.x);
    unsafeAtomicAdd(p + 1, w * v.y);
    unsafeAtomicAdd(p + 2, w * v.z);
    unsafeAtomicAdd(p + 3, w * v.w);
}

// ---------------------------------------------------------------------------
// node epilogue: add self-loop, normalize, bias, optional ELU. one block/node
// ---------------------------------------------------------------------------
__global__ __launch_bounds__(256)
void epilogue_kernel(const float* __restrict__ xW, const float* __restrict__ acc,
                     const float* __restrict__ denom, const float* __restrict__ as_,
                     const float* __restrict__ ad_, const float* __restrict__ bias,
                     float* __restrict__ out, int N, int do_elu) {
    const int i = blockIdx.x;
    const int t = threadIdx.x;
    const int h = t >> 7;
    float e = as_[i * 2 + h] + ad_[i * 2 + h];
    e = e > 0.f ? e : NEG * e;
    const float wself = expf(e);
    const float dn = denom[i * 2 + h] + wself;
    const float v  = acc[(size_t)i * HC + t] + wself * xW[(size_t)i * HC + t];
    float o = v / dn + bias[t];
    if (do_elu) o = o > 0.f ? o : expm1f(o);
    out[(size_t)i * HC + t] = o;
}

// ---------------------------------------------------------------------------
extern "C" void kernel_launch(void* const* d_in, const int* in_sizes, int n_in,
                              void* d_out, int out_size, void* d_ws, size_t ws_size,
                              hipStream_t stream) {
    const float* x      = (const float*)d_in[0];
    const int*   ei     = (const int*)d_in[1];
    const float* W1     = (const float*)d_in[2];
    const float* a_src1 = (const float*)d_in[3];
    const float* a_dst1 = (const float*)d_in[4];
    const float* b1     = (const float*)d_in[5];
    const float* W2     = (const float*)d_in[6];
    const float* a_src2 = (const float*)d_in[7];
    const float* a_dst2 = (const float*)d_in[8];
    const float* b2     = (const float*)d_in[9];
    float* out = (float*)d_out;

    const int N  = in_sizes[0] / 128;   // 50000
    const int E  = in_sizes[1] / 2;     // 800000
    const int K1 = in_sizes[2] / HC;    // 128
    const int* src = ei;
    const int* dst = ei + E;

    // workspace layout
    float* bufA = (float*)d_ws;                 // N*HC  (xW)
    float* bufB = bufA + (size_t)N * HC;        // N*HC  (acc -> h)
    float* as_b = bufB + (size_t)N * HC;        // N*2
    float* ad_b = as_b + (size_t)N * 2;         // N*2
    float* dn_b = ad_b + (size_t)N * 2;         // N*2

    const dim3 ggrid((N + 63) / 64, HC / 64);

    // ---- layer 1 ----
    gemm_kernel<<<ggrid, 256, 0, stream>>>(x, W1, bufA, N, K1);
    alpha_kernel<<<(N + 3) / 4, 256, 0, stream>>>(bufA, a_src1, a_dst1, as_b, ad_b, N);
    hipMemsetAsync(bufB, 0, (size_t)N * HC * sizeof(float), stream);
    hipMemsetAsync(dn_b, 0, (size_t)N * 2 * sizeof(float), stream);
    edge_kernel<<<(E + 3) / 4, 256, 0, stream>>>(src, dst, bufA, as_b, ad_b, bufB, dn_b, E);
    epilogue_kernel<<<N, 256, 0, stream>>>(bufA, bufB, dn_b, as_b, ad_b, b1, bufB, N, 1);

    // ---- layer 2 ----
    gemm_kernel<<<ggrid, 256, 0, stream>>>(bufB, W2, bufA, N, HC);
    alpha_kernel<<<(N + 3) / 4, 256, 0, stream>>>(bufA, a_src2, a_dst2, as_b, ad_b, N);
    hipMemsetAsync(bufB, 0, (size_t)N * HC * sizeof(float), stream);
    hipMemsetAsync(dn_b, 0, (size_t)N * 2 * sizeof(float), stream);
    edge_kernel<<<(E + 3) / 4, 256, 0, stream>>>(src, dst, bufA, as_b, ad_b, bufB, dn_b, E);
    epilogue_kernel<<<N, 256, 0, stream>>>(bufA, bufB, dn_b, as_b, ad_b, b2, out, N, 0);
}

// Round 4
// 527.424 us; speedup vs baseline: 10.6687x; 10.6687x over previous
//
#include <hip/hip_runtime.h>
#include <math.h>

#define HEADS 2
#define CH    128          // per-head channels
#define HC    256          // HEADS*CH
#define NEG   0.2f         // leaky_relu slope

// ---------------------------------------------------------------------------
// GEMM: C[N,HC] = A[N,K] @ W[K,HC]   (fp32, 64x64 tile, BK=32, 256 thr, 4x4/thr)
// ---------------------------------------------------------------------------
__global__ __launch_bounds__(256)
void gemm_kernel(const float* __restrict__ A, const float* __restrict__ W,
                 float* __restrict__ C, int N, int K) {
    __shared__ float As[32][68];
    __shared__ float Ws[32][68];
    const int t    = threadIdx.x;
    const int row0 = blockIdx.x * 64;
    const int col0 = blockIdx.y * 64;
    const int tm   = t >> 4;
    const int tn   = t & 15;

    float acc[4][4] = {};

    for (int kk = 0; kk < K; kk += 32) {
        {
            const int r  = t >> 3;
            const int c4 = (t & 7) * 4;
            #pragma unroll
            for (int half = 0; half < 2; ++half) {
                const int rr   = r + half * 32;
                const int grow = row0 + rr;
                float4 v = make_float4(0.f, 0.f, 0.f, 0.f);
                if (grow < N)
                    v = *reinterpret_cast<const float4*>(&A[(size_t)grow * K + kk + c4]);
                As[c4 + 0][rr] = v.x; As[c4 + 1][rr] = v.y;
                As[c4 + 2][rr] = v.z; As[c4 + 3][rr] = v.w;
            }
        }
        {
            const int r  = t >> 4;
            const int c4 = (t & 15) * 4;
            #pragma unroll
            for (int half = 0; half < 2; ++half) {
                const int rr = r + half * 16;
                float4 v = *reinterpret_cast<const float4*>(
                    &W[(size_t)(kk + rr) * HC + col0 + c4]);
                *reinterpret_cast<float4*>(&Ws[rr][c4]) = v;
            }
        }
        __syncthreads();

        #pragma unroll 8
        for (int k = 0; k < 32; ++k) {
            float4 av = *reinterpret_cast<const float4*>(&As[k][tm * 4]);
            float4 bv = *reinterpret_cast<const float4*>(&Ws[k][tn * 4]);
            float a[4] = {av.x, av.y, av.z, av.w};
            float b[4] = {bv.x, bv.y, bv.z, bv.w};
            #pragma unroll
            for (int i = 0; i < 4; ++i)
                #pragma unroll
                for (int j = 0; j < 4; ++j)
                    acc[i][j] = fmaf(a[i], b[j], acc[i][j]);
        }
        __syncthreads();
    }

    #pragma unroll
    for (int i = 0; i < 4; ++i) {
        const int grow = row0 + tm * 4 + i;
        if (grow < N) {
            float4 v = make_float4(acc[i][0], acc[i][1], acc[i][2], acc[i][3]);
            *reinterpret_cast<float4*>(&C[(size_t)grow * HC + col0 + tn * 4]) = v;
        }
    }
}

// ---------------------------------------------------------------------------
// alpha: as[n,h] = dot(xW[n,h,:], a_src[h,:]);  ad likewise. one wave / node
// ---------------------------------------------------------------------------
__global__ __launch_bounds__(256)
void alpha_kernel(const float* __restrict__ xW, const float* __restrict__ a_src,
                  const float* __restrict__ a_dst, float* __restrict__ as_out,
                  float* __restrict__ ad_out, int N) {
    const int wid  = (blockIdx.x * 256 + threadIdx.x) >> 6;
    const int lane = threadIdx.x & 63;
    if (wid >= N) return;
    const int h  = lane >> 5;
    const int c0 = (lane & 31) * 4;
    const float4 v  = *reinterpret_cast<const float4*>(&xW[(size_t)wid * HC + lane * 4]);
    const float4 s4 = *reinterpret_cast<const float4*>(&a_src[h * CH + c0]);
    const float4 d4 = *reinterpret_cast<const float4*>(&a_dst[h * CH + c0]);
    float s = v.x * s4.x + v.y * s4.y + v.z * s4.z + v.w * s4.w;
    float d = v.x * d4.x + v.y * d4.y + v.z * d4.z + v.w * d4.w;
    #pragma unroll
    for (int m = 1; m <= 16; m <<= 1) {
        s += __shfl_xor(s, m);
        d += __shfl_xor(d, m);
    }
    if ((lane & 31) == 0) {
        as_out[wid * 2 + h] = s;
        ad_out[wid * 2 + h] = d;
    }
}

// ---------------------------------------------------------------------------
// CSR build: histogram -> 2-level exclusive scan -> scatter (by destination)
// ---------------------------------------------------------------------------
__global__ __launch_bounds__(256)
void hist_kernel(const int* __restrict__ dst, int* __restrict__ counts, int E) {
    const int e = blockIdx.x * 256 + threadIdx.x;
    if (e < E) atomicAdd(&counts[dst[e]], 1);
}

// per-256-chunk exclusive scan, in place; chunk totals out
__global__ __launch_bounds__(256)
void scan_local_kernel(int* __restrict__ data, int* __restrict__ chunk_sum, int N) {
    __shared__ int s[256];
    const int t   = threadIdx.x;
    const int idx = blockIdx.x * 256 + t;
    const int v   = (idx < N) ? data[idx] : 0;
    s[t] = v;
    __syncthreads();
    #pragma unroll
    for (int off = 1; off < 256; off <<= 1) {
        int x = (t >= off) ? s[t - off] : 0;
        __syncthreads();
        s[t] += x;
        __syncthreads();
    }
    if (idx < N) data[idx] = s[t] - v;        // exclusive
    if (t == 255) chunk_sum[blockIdx.x] = s[255];
}

// scan chunk sums (nb <= 256), in place exclusive
__global__ __launch_bounds__(256)
void scan_chunks_kernel(int* __restrict__ chunk, int nb) {
    __shared__ int s[256];
    const int t = threadIdx.x;
    const int v = (t < nb) ? chunk[t] : 0;
    s[t] = v;
    __syncthreads();
    #pragma unroll
    for (int off = 1; off < 256; off <<= 1) {
        int x = (t >= off) ? s[t - off] : 0;
        __syncthreads();
        s[t] += x;
        __syncthreads();
    }
    if (t < nb) chunk[t] = s[t] - v;
}

__global__ __launch_bounds__(256)
void add_offsets_kernel(const int* __restrict__ excl, const int* __restrict__ chunk_excl,
                        int* __restrict__ row_ptr, int* __restrict__ cursor,
                        int N, int E) {
    const int idx = blockIdx.x * 256 + threadIdx.x;
    if (idx < N) {
        const int rp = excl[idx] + chunk_excl[idx >> 8];
        row_ptr[idx] = rp;
        cursor[idx]  = rp;
    }
    if (idx == 0) row_ptr[N] = E;
}

__global__ __launch_bounds__(256)
void scatter_kernel(const int* __restrict__ src, const int* __restrict__ dst,
                    int* __restrict__ cursor, int* __restrict__ col_idx, int E) {
    const int e = blockIdx.x * 256 + threadIdx.x;
    if (e < E) {
        const int pos = atomicAdd(&cursor[dst[e]], 1);
        col_idx[pos] = src[e];
    }
}

// ---------------------------------------------------------------------------
// gather aggregation + fused epilogue: one wave per target node.
//   acc = sum_j exp(lrelu(as[j]+ad[i])) * xW[j]  (+ self loop)
//   out = acc/denom + bias  (optional ELU)
// ---------------------------------------------------------------------------
__global__ __launch_bounds__(256)
void agg_kernel(const int* __restrict__ row_ptr, const int* __restrict__ col_idx,
                const float* __restrict__ xW, const float* __restrict__ as_,
                const float* __restrict__ ad_, const float* __restrict__ bias,
                float* __restrict__ out, int N, int do_elu) {
    const int wid  = (blockIdx.x * 256 + threadIdx.x) >> 6;
    const int lane = threadIdx.x & 63;
    if (wid >= N) return;
    const int i = wid;
    const int h = lane >> 5;
    const float adi = ad_[i * 2 + h];

    float4 acc = make_float4(0.f, 0.f, 0.f, 0.f);
    float dn = 0.f;

    const int beg = row_ptr[i];
    const int end = row_ptr[i + 1];
    for (int k = beg; k < end; ++k) {
        const int j = col_idx[k];
        float e = as_[j * 2 + h] + adi;
        e = e > 0.f ? e : NEG * e;
        const float w = expf(e);
        const float4 v = *reinterpret_cast<const float4*>(&xW[(size_t)j * HC + lane * 4]);
        acc.x = fmaf(w, v.x, acc.x);
        acc.y = fmaf(w, v.y, acc.y);
        acc.z = fmaf(w, v.z, acc.z);
        acc.w = fmaf(w, v.w, acc.w);
        dn += w;
    }
    // self loop
    {
        float e = as_[i * 2 + h] + adi;
        e = e > 0.f ? e : NEG * e;
        const float w = expf(e);
        const float4 v = *reinterpret_cast<const float4*>(&xW[(size_t)i * HC + lane * 4]);
        acc.x = fmaf(w, v.x, acc.x);
        acc.y = fmaf(w, v.y, acc.y);
        acc.z = fmaf(w, v.z, acc.z);
        acc.w = fmaf(w, v.w, acc.w);
        dn += w;
    }
    const float inv = 1.f / dn;
    const float4 b4 = *reinterpret_cast<const float4*>(&bias[lane * 4]);
    float o0 = acc.x * inv + b4.x;
    float o1 = acc.y * inv + b4.y;
    float o2 = acc.z * inv + b4.z;
    float o3 = acc.w * inv + b4.w;
    if (do_elu) {
        o0 = o0 > 0.f ? o0 : expm1f(o0);
        o1 = o1 > 0.f ? o1 : expm1f(o1);
        o2 = o2 > 0.f ? o2 : expm1f(o2);
        o3 = o3 > 0.f ? o3 : expm1f(o3);
    }
    *reinterpret_cast<float4*>(&out[(size_t)i * HC + lane * 4]) =
        make_float4(o0, o1, o2, o3);
}

// ---------------------------------------------------------------------------
extern "C" void kernel_launch(void* const* d_in, const int* in_sizes, int n_in,
                              void* d_out, int out_size, void* d_ws, size_t ws_size,
                              hipStream_t stream) {
    const float* x      = (const float*)d_in[0];
    const int*   ei     = (const int*)d_in[1];
    const float* W1     = (const float*)d_in[2];
    const float* a_src1 = (const float*)d_in[3];
    const float* a_dst1 = (const float*)d_in[4];
    const float* b1     = (const float*)d_in[5];
    const float* W2     = (const float*)d_in[6];
    const float* a_src2 = (const float*)d_in[7];
    const float* a_dst2 = (const float*)d_in[8];
    const float* b2     = (const float*)d_in[9];
    float* out = (float*)d_out;

    const int N  = in_sizes[0] / 128;   // 50000
    const int E  = in_sizes[1] / 2;     // 800000
    const int K1 = in_sizes[2] / HC;    // 128
    const int* src = ei;
    const int* dst = ei + E;

    // workspace layout
    float* bufA  = (float*)d_ws;                 // N*HC  (xW)
    float* bufB  = bufA + (size_t)N * HC;        // N*HC  (h)
    float* as_b  = bufB + (size_t)N * HC;        // N*2
    float* ad_b  = as_b + (size_t)N * 2;         // N*2
    int*   tmp   = (int*)(ad_b + (size_t)N * 2); // N   (counts -> excl scan)
    int*   chunk = tmp + N;                      // 256 (chunk sums)
    int*   rowp  = chunk + 256;                  // N+1
    int*   curs  = rowp + (N + 1);               // N
    int*   colx  = curs + N;                     // E

    const int nb = (N + 255) / 256;

    // ---- CSR build (shared by both layers) ----
    hipMemsetAsync(tmp, 0, (size_t)N * sizeof(int), stream);
    hist_kernel<<<(E + 255) / 256, 256, 0, stream>>>(dst, tmp, E);
    scan_local_kernel<<<nb, 256, 0, stream>>>(tmp, chunk, N);
    scan_chunks_kernel<<<1, 256, 0, stream>>>(chunk, nb);
    add_offsets_kernel<<<nb, 256, 0, stream>>>(tmp, chunk, rowp, curs, N, E);
    scatter_kernel<<<(E + 255) / 256, 256, 0, stream>>>(src, dst, curs, colx, E);

    const dim3 ggrid((N + 63) / 64, HC / 64);
    const int  agrid = (N + 3) / 4;   // one wave per node, 4 waves/block

    // ---- layer 1 ----
    gemm_kernel<<<ggrid, 256, 0, stream>>>(x, W1, bufA, N, K1);
    alpha_kernel<<<agrid, 256, 0, stream>>>(bufA, a_src1, a_dst1, as_b, ad_b, N);
    agg_kernel<<<agrid, 256, 0, stream>>>(rowp, colx, bufA, as_b, ad_b, b1, bufB, N, 1);

    // ---- layer 2 ----
    gemm_kernel<<<ggrid, 256, 0, stream>>>(bufB, W2, bufA, N, HC);
    alpha_kernel<<<agrid, 256, 0, stream>>>(bufA, a_src2, a_dst2, as_b, ad_b, N);
    agg_kernel<<<agrid, 256, 0, stream>>>(rowp, colx, bufA, as_b, ad_b, b2, out, N, 0);
}

// Round 6
// 461.956 us; speedup vs baseline: 12.1807x; 1.1417x over previous
//
#include <hip/hip_runtime.h>
#include <math.h>

#define HEADS 2
#define CH    128          // per-head channels
#define HC    256          // HEADS*CH
#define NEG   0.2f         // leaky_relu slope

typedef __attribute__((ext_vector_type(8))) short  bfrag8;   // 8 bf16 (4 VGPR) MFMA operand
typedef __attribute__((ext_vector_type(4))) float  f32x4;    // MFMA accumulator

// round-to-nearest-even fp32 -> bf16 (as raw u16)
__device__ inline unsigned short f2bf_rne(float x) {
    unsigned u = __float_as_uint(x);
    u += 0x7fffu + ((u >> 16) & 1u);
    return (unsigned short)(u >> 16);
}
// 2-term split: x ~= hi + lo (both bf16); residual ~2^-16 relative
__device__ inline void split2(float x, unsigned short& hi, unsigned short& lo) {
    unsigned u = __float_as_uint(x);
    unsigned r = u + 0x7fffu + ((u >> 16) & 1u);
    unsigned short h = (unsigned short)(r >> 16);
    float hf = __uint_as_float((unsigned)h << 16);
    hi = h;
    lo = f2bf_rne(x - hf);
}

// ---------------------------------------------------------------------------
// W pre-split: W[K][HC] fp32 -> Wthi/Wtlo[HC][K] bf16 (k-contiguous, transposed)
// ---------------------------------------------------------------------------
__global__ __launch_bounds__(256)
void wsplit_kernel(const float* __restrict__ W, unsigned short* __restrict__ Whi,
                   unsigned short* __restrict__ Wlo, int K) {
    const int idx = blockIdx.x * 256 + threadIdx.x;
    if (idx >= K * HC) return;
    const int k = idx >> 8;          // HC == 256
    const int n = idx & 255;
    unsigned short h, l;
    split2(W[idx], h, l);
    Whi[(size_t)n * K + k] = h;
    Wlo[(size_t)n * K + k] = l;
}

// ---------------------------------------------------------------------------
// GEMM via split-bf16 MFMA: C[M,HC] = A[M,K] @ W[K,HC]
// tile 128x128, BK=32, 4 waves (2x2), wave tile 64x64 (4x4 16x16 frags)
// A·B ~= hiA·hiB + hiA·loB + loA·hiB, fp32 accumulate (error ~2^-16 rel)
// ---------------------------------------------------------------------------
__global__ __launch_bounds__(256)
void gemm_mfma_kernel(const float* __restrict__ A,
                      const unsigned short* __restrict__ Wthi,
                      const unsigned short* __restrict__ Wtlo,
                      float* __restrict__ C, int M, int K) {
    // stride 40 bf16 = 80 B: keeps b128 frag reads 16B-aligned, ~2-way banks
    __shared__ unsigned short Ah[128][40];
    __shared__ unsigned short Al[128][40];
    __shared__ unsigned short Bh[128][40];
    __shared__ unsigned short Bl[128][40];

    const int t    = threadIdx.x;
    const int row0 = blockIdx.x * 128;
    const int col0 = blockIdx.y * 128;
    const int lane = t & 63;
    const int wid  = t >> 6;
    const int wr   = wid >> 1;       // wave row 0..1
    const int wc   = wid & 1;        // wave col 0..1

    f32x4 acc[4][4] = {};

    const int ar  = t >> 3;          // A staging: base row 0..31
    const int ac4 = (t & 7) * 4;     // A staging: k offset 0..28
    const int bcol   = t >> 1;       // B staging: col 0..127
    const int bplane = t & 1;        // 0 = hi, 1 = lo

    for (int kk = 0; kk < K; kk += 32) {
        // ---- stage A (128 x 32 fp32), split into hi/lo bf16 ----
        #pragma unroll
        for (int rep = 0; rep < 4; ++rep) {
            const int row = ar + rep * 32;
            const int gr  = row0 + row;
            float4 v = make_float4(0.f, 0.f, 0.f, 0.f);
            if (gr < M)
                v = *reinterpret_cast<const float4*>(&A[(size_t)gr * K + kk + ac4]);
            ushort4 hv, lv;
            split2(v.x, hv.x, lv.x);
            split2(v.y, hv.y, lv.y);
            split2(v.z, hv.z, lv.z);
            split2(v.w, hv.w, lv.w);
            *reinterpret_cast<ushort4*>(&Ah[row][ac4]) = hv;
            *reinterpret_cast<ushort4*>(&Al[row][ac4]) = lv;
        }
        // ---- stage B (128 cols x 32 k bf16, already transposed in global) ----
        {
            const unsigned short* srcp =
                (bplane ? Wtlo : Wthi) + (size_t)(col0 + bcol) * K + kk;
            unsigned short (*dst)[40] = bplane ? Bl : Bh;
            #pragma unroll
            for (int q = 0; q < 4; ++q) {
                bfrag8 v = *reinterpret_cast<const bfrag8*>(srcp + q * 8);
                *reinterpret_cast<bfrag8*>(&dst[bcol][q * 8]) = v;
            }
        }
        __syncthreads();

        // ---- fragment loads ----
        bfrag8 ah[4], al[4], bh[4], bl[4];
        const int ko = (lane >> 4) * 8;
        #pragma unroll
        for (int m = 0; m < 4; ++m) {
            const int row = wr * 64 + m * 16 + (lane & 15);
            ah[m] = *reinterpret_cast<const bfrag8*>(&Ah[row][ko]);
            al[m] = *reinterpret_cast<const bfrag8*>(&Al[row][ko]);
        }
        #pragma unroll
        for (int n = 0; n < 4; ++n) {
            const int col = wc * 64 + n * 16 + (lane & 15);
            bh[n] = *reinterpret_cast<const bfrag8*>(&Bh[col][ko]);
            bl[n] = *reinterpret_cast<const bfrag8*>(&Bl[col][ko]);
        }

        // ---- 3-pass split MFMA ----
        #pragma unroll
        for (int m = 0; m < 4; ++m)
            #pragma unroll
            for (int n = 0; n < 4; ++n) {
                acc[m][n] = __builtin_amdgcn_mfma_f32_16x16x32_bf16(al[m], bh[n], acc[m][n], 0, 0, 0);
                acc[m][n] = __builtin_amdgcn_mfma_f32_16x16x32_bf16(ah[m], bl[n], acc[m][n], 0, 0, 0);
                acc[m][n] = __builtin_amdgcn_mfma_f32_16x16x32_bf16(ah[m], bh[n], acc[m][n], 0, 0, 0);
            }
        __syncthreads();
    }

    // ---- epilogue: C/D layout col=lane&15, row=(lane>>4)*4+reg ----
    #pragma unroll
    for (int m = 0; m < 4; ++m) {
        #pragma unroll
        for (int reg = 0; reg < 4; ++reg) {
            const int gr = row0 + wr * 64 + m * 16 + (lane >> 4) * 4 + reg;
            if (gr < M) {
                #pragma unroll
                for (int n = 0; n < 4; ++n) {
                    const int gc = col0 + wc * 64 + n * 16 + (lane & 15);
                    C[(size_t)gr * HC + gc] = acc[m][n][reg];
                }
            }
        }
    }
}

// ---------------------------------------------------------------------------
// alpha: as[n,h] = dot(xW[n,h,:], a_src[h,:]);  ad likewise. one wave / node
// ---------------------------------------------------------------------------
__global__ __launch_bounds__(256)
void alpha_kernel(const float* __restrict__ xW, const float* __restrict__ a_src,
                  const float* __restrict__ a_dst, float* __restrict__ as_out,
                  float* __restrict__ ad_out, int N) {
    const int wid  = (blockIdx.x * 256 + threadIdx.x) >> 6;
    const int lane = threadIdx.x & 63;
    if (wid >= N) return;
    const int h  = lane >> 5;
    const int c0 = (lane & 31) * 4;
    const float4 v  = *reinterpret_cast<const float4*>(&xW[(size_t)wid * HC + lane * 4]);
    const float4 s4 = *reinterpret_cast<const float4*>(&a_src[h * CH + c0]);
    const float4 d4 = *reinterpret_cast<const float4*>(&a_dst[h * CH + c0]);
    float s = v.x * s4.x + v.y * s4.y + v.z * s4.z + v.w * s4.w;
    float d = v.x * d4.x + v.y * d4.y + v.z * d4.z + v.w * d4.w;
    #pragma unroll
    for (int m = 1; m <= 16; m <<= 1) {
        s += __shfl_xor(s, m);
        d += __shfl_xor(d, m);
    }
    if ((lane & 31) == 0) {
        as_out[wid * 2 + h] = s;
        ad_out[wid * 2 + h] = d;
    }
}

// ---------------------------------------------------------------------------
// CSR build: histogram -> 2-level exclusive scan -> scatter (by destination)
// ---------------------------------------------------------------------------
__global__ __launch_bounds__(256)
void hist_kernel(const int* __restrict__ dst, int* __restrict__ counts, int E) {
    const int e = blockIdx.x * 256 + threadIdx.x;
    if (e < E) atomicAdd(&counts[dst[e]], 1);
}

__global__ __launch_bounds__(256)
void scan_local_kernel(int* __restrict__ data, int* __restrict__ chunk_sum, int N) {
    __shared__ int s[256];
    const int t   = threadIdx.x;
    const int idx = blockIdx.x * 256 + t;
    const int v   = (idx < N) ? data[idx] : 0;
    s[t] = v;
    __syncthreads();
    #pragma unroll
    for (int off = 1; off < 256; off <<= 1) {
        int x = (t >= off) ? s[t - off] : 0;
        __syncthreads();
        s[t] += x;
        __syncthreads();
    }
    if (idx < N) data[idx] = s[t] - v;        // exclusive
    if (t == 255) chunk_sum[blockIdx.x] = s[255];
}

__global__ __launch_bounds__(256)
void scan_chunks_kernel(int* __restrict__ chunk, int nb) {
    __shared__ int s[256];
    const int t = threadIdx.x;
    const int v = (t < nb) ? chunk[t] : 0;
    s[t] = v;
    __syncthreads();
    #pragma unroll
    for (int off = 1; off < 256; off <<= 1) {
        int x = (t >= off) ? s[t - off] : 0;
        __syncthreads();
        s[t] += x;
        __syncthreads();
    }
    if (t < nb) chunk[t] = s[t] - v;
}

__global__ __launch_bounds__(256)
void add_offsets_kernel(const int* __restrict__ excl, const int* __restrict__ chunk_excl,
                        int* __restrict__ row_ptr, int* __restrict__ cursor,
                        int N, int E) {
    const int idx = blockIdx.x * 256 + threadIdx.x;
    if (idx < N) {
        const int rp = excl[idx] + chunk_excl[idx >> 8];
        row_ptr[idx] = rp;
        cursor[idx]  = rp;
    }
    if (idx == 0) row_ptr[N] = E;
}

__global__ __launch_bounds__(256)
void scatter_kernel(const int* __restrict__ src, const int* __restrict__ dst,
                    int* __restrict__ cursor, int* __restrict__ col_idx, int E) {
    const int e = blockIdx.x * 256 + threadIdx.x;
    if (e < E) {
        const int pos = atomicAdd(&cursor[dst[e]], 1);
        col_idx[pos] = src[e];
    }
}

// ---------------------------------------------------------------------------
// gather aggregation + fused epilogue: one wave per target node.
// ---------------------------------------------------------------------------
__global__ __launch_bounds__(256)
void agg_kernel(const int* __restrict__ row_ptr, const int* __restrict__ col_idx,
                const float* __restrict__ xW, const float* __restrict__ as_,
                const float* __restrict__ ad_, const float* __restrict__ bias,
                float* __restrict__ out, int N, int do_elu) {
    const int wid  = (blockIdx.x * 256 + threadIdx.x) >> 6;
    const int lane = threadIdx.x & 63;
    if (wid >= N) return;
    const int i = wid;
    const int h = lane >> 5;
    const float adi = ad_[i * 2 + h];

    float4 acc = make_float4(0.f, 0.f, 0.f, 0.f);
    float dn = 0.f;

    const int beg = row_ptr[i];
    const int end = row_ptr[i + 1];
    for (int k = beg; k < end; ++k) {
        const int j = col_idx[k];
        float e = as_[j * 2 + h] + adi;
        e = e > 0.f ? e : NEG * e;
        const float w = expf(e);
        const float4 v = *reinterpret_cast<const float4*>(&xW[(size_t)j * HC + lane * 4]);
        acc.x = fmaf(w, v.x, acc.x);
        acc.y = fmaf(w, v.y, acc.y);
        acc.z = fmaf(w, v.z, acc.z);
        acc.w = fmaf(w, v.w, acc.w);
        dn += w;
    }
    // self loop
    {
        float e = as_[i * 2 + h] + adi;
        e = e > 0.f ? e : NEG * e;
        const float w = expf(e);
        const float4 v = *reinterpret_cast<const float4*>(&xW[(size_t)i * HC + lane * 4]);
        acc.x = fmaf(w, v.x, acc.x);
        acc.y = fmaf(w, v.y, acc.y);
        acc.z = fmaf(w, v.z, acc.z);
        acc.w = fmaf(w, v.w, acc.w);
        dn += w;
    }
    const float inv = 1.f / dn;
    const float4 b4 = *reinterpret_cast<const float4*>(&bias[lane * 4]);
    float o0 = acc.x * inv + b4.x;
    float o1 = acc.y * inv + b4.y;
    float o2 = acc.z * inv + b4.z;
    float o3 = acc.w * inv + b4.w;
    if (do_elu) {
        o0 = o0 > 0.f ? o0 : expm1f(o0);
        o1 = o1 > 0.f ? o1 : expm1f(o1);
        o2 = o2 > 0.f ? o2 : expm1f(o2);
        o3 = o3 > 0.f ? o3 : expm1f(o3);
    }
    *reinterpret_cast<float4*>(&out[(size_t)i * HC + lane * 4]) =
        make_float4(o0, o1, o2, o3);
}

// ---------------------------------------------------------------------------
extern "C" void kernel_launch(void* const* d_in, const int* in_sizes, int n_in,
                              void* d_out, int out_size, void* d_ws, size_t ws_size,
                              hipStream_t stream) {
    const float* x      = (const float*)d_in[0];
    const int*   ei     = (const int*)d_in[1];
    const float* W1     = (const float*)d_in[2];
    const float* a_src1 = (const float*)d_in[3];
    const float* a_dst1 = (const float*)d_in[4];
    const float* b1     = (const float*)d_in[5];
    const float* W2     = (const float*)d_in[6];
    const float* a_src2 = (const float*)d_in[7];
    const float* a_dst2 = (const float*)d_in[8];
    const float* b2     = (const float*)d_in[9];
    float* out = (float*)d_out;

    const int Nn = in_sizes[0] / 128;   // 50000 nodes
    const int E  = in_sizes[1] / 2;     // 800000 edges
    const int K1 = in_sizes[2] / HC;    // 128
    const int* src = ei;
    const int* dst = ei + E;

    // workspace layout
    float* bufA  = (float*)d_ws;                  // Nn*HC  (xW)
    float* bufB  = bufA + (size_t)Nn * HC;        // Nn*HC  (h)
    float* as_b  = bufB + (size_t)Nn * HC;        // Nn*2
    float* ad_b  = as_b + (size_t)Nn * 2;         // Nn*2
    int*   tmp   = (int*)(ad_b + (size_t)Nn * 2); // Nn  (counts -> excl scan)
    int*   chunk = tmp + Nn;                      // 256
    int*   rowp  = chunk + 256;                   // Nn+1
    int*   curs  = rowp + (Nn + 1);               // Nn
    int*   colx  = curs + Nn;                     // E
    unsigned short* wt1hi = (unsigned short*)(colx + E);   // HC*K1
    unsigned short* wt1lo = wt1hi + (size_t)HC * K1;
    unsigned short* wt2hi = wt1lo + (size_t)HC * K1;       // HC*HC
    unsigned short* wt2lo = wt2hi + (size_t)HC * HC;

    const int nb = (Nn + 255) / 256;

    // ---- W pre-split (tiny) ----
    wsplit_kernel<<<(K1 * HC + 255) / 256, 256, 0, stream>>>(W1, wt1hi, wt1lo, K1);
    wsplit_kernel<<<(HC * HC + 255) / 256, 256, 0, stream>>>(W2, wt2hi, wt2lo, HC);

    // ---- CSR build (shared by both layers) ----
    hipMemsetAsync(tmp, 0, (size_t)Nn * sizeof(int), stream);
    hist_kernel<<<(E + 255) / 256, 256, 0, stream>>>(dst, tmp, E);
    scan_local_kernel<<<nb, 256, 0, stream>>>(tmp, chunk, Nn);
    scan_chunks_kernel<<<1, 256, 0, stream>>>(chunk, nb);
    add_offsets_kernel<<<nb, 256, 0, stream>>>(tmp, chunk, rowp, curs, Nn, E);
    scatter_kernel<<<(E + 255) / 256, 256, 0, stream>>>(src, dst, curs, colx, E);

    const dim3 ggrid((Nn + 127) / 128, HC / 128);
    const int  agrid = (Nn + 3) / 4;   // one wave per node

    // ---- layer 1 ----
    gemm_mfma_kernel<<<ggrid, 256, 0, stream>>>(x, wt1hi, wt1lo, bufA, Nn, K1);
    alpha_kernel<<<agrid, 256, 0, stream>>>(bufA, a_src1, a_dst1, as_b, ad_b, Nn);
    agg_kernel<<<agrid, 256, 0, stream>>>(rowp, colx, bufA, as_b, ad_b, b1, bufB, Nn, 1);

    // ---- layer 2 ----
    gemm_mfma_kernel<<<ggrid, 256, 0, stream>>>(bufB, wt2hi, wt2lo, bufA, Nn, HC);
    alpha_kernel<<<agrid, 256, 0, stream>>>(bufA, a_src2, a_dst2, as_b, ad_b, Nn);
    agg_kernel<<<agrid, 256, 0, stream>>>(rowp, colx, bufA, as_b, ad_b, b2, out, Nn, 0);
}

// Round 7
// 382.508 us; speedup vs baseline: 14.7106x; 1.2077x over previous
//
#include <hip/hip_runtime.h>
#include <math.h>

#define HEADS 2
#define CH    128          // per-head channels
#define HC    256          // HEADS*CH
#define NEG   0.2f         // leaky_relu slope

typedef __attribute__((ext_vector_type(8))) short  bfrag8;   // 8 bf16 (4 VGPR) MFMA operand
typedef __attribute__((ext_vector_type(4))) float  f32x4;    // MFMA accumulator

// round-to-nearest-even fp32 -> bf16 (as raw u16)
__device__ inline unsigned short f2bf_rne(float x) {
    unsigned u = __float_as_uint(x);
    u += 0x7fffu + ((u >> 16) & 1u);
    return (unsigned short)(u >> 16);
}
// 2-term split: x ~= hi + lo (both bf16); residual ~2^-16 relative
__device__ inline void split2(float x, unsigned short& hi, unsigned short& lo) {
    unsigned u = __float_as_uint(x);
    unsigned r = u + 0x7fffu + ((u >> 16) & 1u);
    unsigned short h = (unsigned short)(r >> 16);
    float hf = __uint_as_float((unsigned)h << 16);
    hi = h;
    lo = f2bf_rne(x - hf);
}

// ---------------------------------------------------------------------------
// W pre-split: W[K][HC] fp32 -> Wthi/Wtlo[HC][K] bf16 (k-contiguous, transposed)
// ---------------------------------------------------------------------------
__global__ __launch_bounds__(256)
void wsplit_kernel(const float* __restrict__ W, unsigned short* __restrict__ Whi,
                   unsigned short* __restrict__ Wlo, int K) {
    const int idx = blockIdx.x * 256 + threadIdx.x;
    if (idx >= K * HC) return;
    const int k = idx >> 8;          // HC == 256
    const int n = idx & 255;
    unsigned short h, l;
    split2(W[idx], h, l);
    Whi[(size_t)n * K + k] = h;
    Wlo[(size_t)n * K + k] = l;
}

// ---------------------------------------------------------------------------
// GEMM via split-bf16 MFMA: C[M,HC] = A[M,K] @ W[K,HC]
// tile 128x128, BK=32, 4 waves (2x2), wave tile 64x64 (4x4 16x16 frags)
// A·B ~= hiA·hiB + hiA·loB + loA·hiB, fp32 accumulate (error ~2^-16 rel)
// ---------------------------------------------------------------------------
__global__ __launch_bounds__(256)
void gemm_mfma_kernel(const float* __restrict__ A,
                      const unsigned short* __restrict__ Wthi,
                      const unsigned short* __restrict__ Wtlo,
                      float* __restrict__ C, int M, int K) {
    __shared__ unsigned short Ah[128][40];
    __shared__ unsigned short Al[128][40];
    __shared__ unsigned short Bh[128][40];
    __shared__ unsigned short Bl[128][40];

    const int t    = threadIdx.x;
    const int row0 = blockIdx.x * 128;
    const int col0 = blockIdx.y * 128;
    const int lane = t & 63;
    const int wid  = t >> 6;
    const int wr   = wid >> 1;       // wave row 0..1
    const int wc   = wid & 1;        // wave col 0..1

    f32x4 acc[4][4] = {};

    const int ar  = t >> 3;          // A staging: base row 0..31
    const int ac4 = (t & 7) * 4;     // A staging: k offset 0..28
    const int bcol   = t >> 1;       // B staging: col 0..127
    const int bplane = t & 1;        // 0 = hi, 1 = lo

    for (int kk = 0; kk < K; kk += 32) {
        // ---- stage A (128 x 32 fp32), split into hi/lo bf16 ----
        #pragma unroll
        for (int rep = 0; rep < 4; ++rep) {
            const int row = ar + rep * 32;
            const int gr  = row0 + row;
            float4 v = make_float4(0.f, 0.f, 0.f, 0.f);
            if (gr < M)
                v = *reinterpret_cast<const float4*>(&A[(size_t)gr * K + kk + ac4]);
            ushort4 hv, lv;
            split2(v.x, hv.x, lv.x);
            split2(v.y, hv.y, lv.y);
            split2(v.z, hv.z, lv.z);
            split2(v.w, hv.w, lv.w);
            *reinterpret_cast<ushort4*>(&Ah[row][ac4]) = hv;
            *reinterpret_cast<ushort4*>(&Al[row][ac4]) = lv;
        }
        // ---- stage B (128 cols x 32 k bf16, already transposed in global) ----
        {
            const unsigned short* srcp =
                (bplane ? Wtlo : Wthi) + (size_t)(col0 + bcol) * K + kk;
            unsigned short (*dst)[40] = bplane ? Bl : Bh;
            #pragma unroll
            for (int q = 0; q < 4; ++q) {
                bfrag8 v = *reinterpret_cast<const bfrag8*>(srcp + q * 8);
                *reinterpret_cast<bfrag8*>(&dst[bcol][q * 8]) = v;
            }
        }
        __syncthreads();

        // ---- fragment loads ----
        bfrag8 ah[4], al[4], bh[4], bl[4];
        const int ko = (lane >> 4) * 8;
        #pragma unroll
        for (int m = 0; m < 4; ++m) {
            const int row = wr * 64 + m * 16 + (lane & 15);
            ah[m] = *reinterpret_cast<const bfrag8*>(&Ah[row][ko]);
            al[m] = *reinterpret_cast<const bfrag8*>(&Al[row][ko]);
        }
        #pragma unroll
        for (int n = 0; n < 4; ++n) {
            const int col = wc * 64 + n * 16 + (lane & 15);
            bh[n] = *reinterpret_cast<const bfrag8*>(&Bh[col][ko]);
            bl[n] = *reinterpret_cast<const bfrag8*>(&Bl[col][ko]);
        }

        // ---- 3-pass split MFMA ----
        #pragma unroll
        for (int m = 0; m < 4; ++m)
            #pragma unroll
            for (int n = 0; n < 4; ++n) {
                acc[m][n] = __builtin_amdgcn_mfma_f32_16x16x32_bf16(al[m], bh[n], acc[m][n], 0, 0, 0);
                acc[m][n] = __builtin_amdgcn_mfma_f32_16x16x32_bf16(ah[m], bl[n], acc[m][n], 0, 0, 0);
                acc[m][n] = __builtin_amdgcn_mfma_f32_16x16x32_bf16(ah[m], bh[n], acc[m][n], 0, 0, 0);
            }
        __syncthreads();
    }

    // ---- epilogue: C/D layout col=lane&15, row=(lane>>4)*4+reg ----
    #pragma unroll
    for (int m = 0; m < 4; ++m) {
        #pragma unroll
        for (int reg = 0; reg < 4; ++reg) {
            const int gr = row0 + wr * 64 + m * 16 + (lane >> 4) * 4 + reg;
            if (gr < M) {
                #pragma unroll
                for (int n = 0; n < 4; ++n) {
                    const int gc = col0 + wc * 64 + n * 16 + (lane & 15);
                    C[(size_t)gr * HC + gc] = acc[m][n][reg];
                }
            }
        }
    }
}

// ---------------------------------------------------------------------------
// alpha + bf16 shadow: as/ad dots, and write xWb = bf16(xW) (fused free pass)
// ---------------------------------------------------------------------------
__global__ __launch_bounds__(256)
void alpha_kernel(const float* __restrict__ xW, const float* __restrict__ a_src,
                  const float* __restrict__ a_dst, float* __restrict__ as_out,
                  float* __restrict__ ad_out, unsigned short* __restrict__ xWb,
                  int N) {
    const int wid  = (blockIdx.x * 256 + threadIdx.x) >> 6;
    const int lane = threadIdx.x & 63;
    if (wid >= N) return;
    const int h  = lane >> 5;
    const int c0 = (lane & 31) * 4;
    const float4 v  = *reinterpret_cast<const float4*>(&xW[(size_t)wid * HC + lane * 4]);
    // bf16 shadow row (coalesced 8 B/lane)
    ushort4 bv;
    bv.x = f2bf_rne(v.x); bv.y = f2bf_rne(v.y);
    bv.z = f2bf_rne(v.z); bv.w = f2bf_rne(v.w);
    *reinterpret_cast<ushort4*>(&xWb[(size_t)wid * HC + lane * 4]) = bv;

    const float4 s4 = *reinterpret_cast<const float4*>(&a_src[h * CH + c0]);
    const float4 d4 = *reinterpret_cast<const float4*>(&a_dst[h * CH + c0]);
    float s = v.x * s4.x + v.y * s4.y + v.z * s4.z + v.w * s4.w;
    float d = v.x * d4.x + v.y * d4.y + v.z * d4.z + v.w * d4.w;
    #pragma unroll
    for (int m = 1; m <= 16; m <<= 1) {
        s += __shfl_xor(s, m);
        d += __shfl_xor(d, m);
    }
    if ((lane & 31) == 0) {
        as_out[wid * 2 + h] = s;
        ad_out[wid * 2 + h] = d;
    }
}

// ---------------------------------------------------------------------------
// CSR build: histogram -> 2-level exclusive scan -> scatter (by destination)
// ---------------------------------------------------------------------------
__global__ __launch_bounds__(256)
void hist_kernel(const int* __restrict__ dst, int* __restrict__ counts, int E) {
    const int e = blockIdx.x * 256 + threadIdx.x;
    if (e < E) atomicAdd(&counts[dst[e]], 1);
}

__global__ __launch_bounds__(256)
void scan_local_kernel(int* __restrict__ data, int* __restrict__ chunk_sum, int N) {
    __shared__ int s[256];
    const int t   = threadIdx.x;
    const int idx = blockIdx.x * 256 + t;
    const int v   = (idx < N) ? data[idx] : 0;
    s[t] = v;
    __syncthreads();
    #pragma unroll
    for (int off = 1; off < 256; off <<= 1) {
        int x = (t >= off) ? s[t - off] : 0;
        __syncthreads();
        s[t] += x;
        __syncthreads();
    }
    if (idx < N) data[idx] = s[t] - v;        // exclusive
    if (t == 255) chunk_sum[blockIdx.x] = s[255];
}

__global__ __launch_bounds__(256)
void scan_chunks_kernel(int* __restrict__ chunk, int nb) {
    __shared__ int s[256];
    const int t = threadIdx.x;
    const int v = (t < nb) ? chunk[t] : 0;
    s[t] = v;
    __syncthreads();
    #pragma unroll
    for (int off = 1; off < 256; off <<= 1) {
        int x = (t >= off) ? s[t - off] : 0;
        __syncthreads();
        s[t] += x;
        __syncthreads();
    }
    if (t < nb) chunk[t] = s[t] - v;
}

__global__ __launch_bounds__(256)
void add_offsets_kernel(const int* __restrict__ excl, const int* __restrict__ chunk_excl,
                        int* __restrict__ row_ptr, int* __restrict__ cursor,
                        int N, int E) {
    const int idx = blockIdx.x * 256 + threadIdx.x;
    if (idx < N) {
        const int rp = excl[idx] + chunk_excl[idx >> 8];
        row_ptr[idx] = rp;
        cursor[idx]  = rp;
    }
    if (idx == 0) row_ptr[N] = E;
}

__global__ __launch_bounds__(256)
void scatter_kernel(const int* __restrict__ src, const int* __restrict__ dst,
                    int* __restrict__ cursor, int* __restrict__ col_idx, int E) {
    const int e = blockIdx.x * 256 + threadIdx.x;
    if (e < E) {
        const int pos = atomicAdd(&cursor[dst[e]], 1);
        col_idx[pos] = src[e];
    }
}

// ---------------------------------------------------------------------------
// gather aggregation + fused epilogue: one wave per target node.
// bf16 messages, 2 edges in flight (lanes 0-31 / 32-63), fp32 self-loop.
// sublane sl=lane&31 covers 8 channels: cb = (sl>>4)*128 + (sl&15)*8
// ---------------------------------------------------------------------------
__global__ __launch_bounds__(256)
void agg_kernel(const int* __restrict__ row_ptr, const int* __restrict__ col_idx,
                const float* __restrict__ xW, const unsigned short* __restrict__ xWb,
                const float* __restrict__ as_, const float* __restrict__ ad_,
                const float* __restrict__ bias, float* __restrict__ out,
                int N, int do_elu) {
    const int wv   = (blockIdx.x * 256 + threadIdx.x) >> 6;
    const int lane = threadIdx.x & 63;
    if (wv >= N) return;
    const int i    = wv;
    const int half = lane >> 5;          // which edge stream
    const int sl   = lane & 31;
    const int hh   = sl >> 4;            // head of this sublane
    const int cb   = hh * 128 + (sl & 15) * 8;   // 8-channel block base
    const float adi = ad_[i * 2 + hh];

    float acc[8] = {};
    float dn = 0.f;

    const int beg = row_ptr[i];
    const int end = row_ptr[i + 1];

    int k = beg + half;
    int j = (k < end) ? col_idx[k] : 0;
    for (; k < end; k += 2) {
        const int jn = (k + 2 < end) ? col_idx[k + 2] : 0;   // prefetch
        float e = as_[j * 2 + hh] + adi;
        e = e > 0.f ? e : NEG * e;
        const float w = expf(e);
        const uint4 q = *reinterpret_cast<const uint4*>(&xWb[(size_t)j * HC + cb]);
        // unpack 8 bf16 -> fp32 (lo ushort = even channel)
        const unsigned qq[4] = {q.x, q.y, q.z, q.w};
        #pragma unroll
        for (int r = 0; r < 4; ++r) {
            const float flo = __uint_as_float(qq[r] << 16);
            const float fhi = __uint_as_float(qq[r] & 0xffff0000u);
            acc[r * 2 + 0] = fmaf(w, flo, acc[r * 2 + 0]);
            acc[r * 2 + 1] = fmaf(w, fhi, acc[r * 2 + 1]);
        }
        dn += w;
        j = jn;
    }

    // merge the two edge streams
    #pragma unroll
    for (int r = 0; r < 8; ++r) acc[r] += __shfl_xor(acc[r], 32);
    dn += __shfl_xor(dn, 32);

    if (lane < 32) {
        // self loop in fp32
        float e = as_[i * 2 + hh] + adi;
        e = e > 0.f ? e : NEG * e;
        const float ws = expf(e);
        const float4 v0 = *reinterpret_cast<const float4*>(&xW[(size_t)i * HC + cb]);
        const float4 v1 = *reinterpret_cast<const float4*>(&xW[(size_t)i * HC + cb + 4]);
        acc[0] = fmaf(ws, v0.x, acc[0]); acc[1] = fmaf(ws, v0.y, acc[1]);
        acc[2] = fmaf(ws, v0.z, acc[2]); acc[3] = fmaf(ws, v0.w, acc[3]);
        acc[4] = fmaf(ws, v1.x, acc[4]); acc[5] = fmaf(ws, v1.y, acc[5]);
        acc[6] = fmaf(ws, v1.z, acc[6]); acc[7] = fmaf(ws, v1.w, acc[7]);
        dn += ws;

        const float inv = 1.f / dn;
        const float4 b0 = *reinterpret_cast<const float4*>(&bias[cb]);
        const float4 b1 = *reinterpret_cast<const float4*>(&bias[cb + 4]);
        float o[8];
        o[0] = acc[0] * inv + b0.x; o[1] = acc[1] * inv + b0.y;
        o[2] = acc[2] * inv + b0.z; o[3] = acc[3] * inv + b0.w;
        o[4] = acc[4] * inv + b1.x; o[5] = acc[5] * inv + b1.y;
        o[6] = acc[6] * inv + b1.z; o[7] = acc[7] * inv + b1.w;
        if (do_elu) {
            #pragma unroll
            for (int r = 0; r < 8; ++r) o[r] = o[r] > 0.f ? o[r] : expm1f(o[r]);
        }
        *reinterpret_cast<float4*>(&out[(size_t)i * HC + cb]) =
            make_float4(o[0], o[1], o[2], o[3]);
        *reinterpret_cast<float4*>(&out[(size_t)i * HC + cb + 4]) =
            make_float4(o[4], o[5], o[6], o[7]);
    }
}

// ---------------------------------------------------------------------------
extern "C" void kernel_launch(void* const* d_in, const int* in_sizes, int n_in,
                              void* d_out, int out_size, void* d_ws, size_t ws_size,
                              hipStream_t stream) {
    const float* x      = (const float*)d_in[0];
    const int*   ei     = (const int*)d_in[1];
    const float* W1     = (const float*)d_in[2];
    const float* a_src1 = (const float*)d_in[3];
    const float* a_dst1 = (const float*)d_in[4];
    const float* b1     = (const float*)d_in[5];
    const float* W2     = (const float*)d_in[6];
    const float* a_src2 = (const float*)d_in[7];
    const float* a_dst2 = (const float*)d_in[8];
    const float* b2     = (const float*)d_in[9];
    float* out = (float*)d_out;

    const int Nn = in_sizes[0] / 128;   // 50000 nodes
    const int E  = in_sizes[1] / 2;     // 800000 edges
    const int K1 = in_sizes[2] / HC;    // 128
    const int* src = ei;
    const int* dst = ei + E;

    // workspace layout
    float* bufA  = (float*)d_ws;                  // Nn*HC  (xW)
    float* bufB  = bufA + (size_t)Nn * HC;        // Nn*HC  (h)
    float* as_b  = bufB + (size_t)Nn * HC;        // Nn*2
    float* ad_b  = as_b + (size_t)Nn * 2;         // Nn*2
    int*   tmp   = (int*)(ad_b + (size_t)Nn * 2); // Nn  (counts -> excl scan)
    int*   chunk = tmp + Nn;                      // 256
    int*   rowp  = chunk + 256;                   // Nn+1
    int*   curs  = rowp + (Nn + 1);               // Nn
    int*   colx  = curs + Nn;                     // E
    unsigned short* wt1hi = (unsigned short*)(colx + E);   // HC*K1
    unsigned short* wt1lo = wt1hi + (size_t)HC * K1;
    unsigned short* wt2hi = wt1lo + (size_t)HC * K1;       // HC*HC
    unsigned short* wt2lo = wt2hi + (size_t)HC * HC;
    unsigned short* xWb   = wt2lo + (size_t)HC * HC;       // Nn*HC bf16 shadow

    const int nb = (Nn + 255) / 256;

    // ---- W pre-split (tiny) ----
    wsplit_kernel<<<(K1 * HC + 255) / 256, 256, 0, stream>>>(W1, wt1hi, wt1lo, K1);
    wsplit_kernel<<<(HC * HC + 255) / 256, 256, 0, stream>>>(W2, wt2hi, wt2lo, HC);

    // ---- CSR build (shared by both layers) ----
    hipMemsetAsync(tmp, 0, (size_t)Nn * sizeof(int), stream);
    hist_kernel<<<(E + 255) / 256, 256, 0, stream>>>(dst, tmp, E);
    scan_local_kernel<<<nb, 256, 0, stream>>>(tmp, chunk, Nn);
    scan_chunks_kernel<<<1, 256, 0, stream>>>(chunk, nb);
    add_offsets_kernel<<<nb, 256, 0, stream>>>(tmp, chunk, rowp, curs, Nn, E);
    scatter_kernel<<<(E + 255) / 256, 256, 0, stream>>>(src, dst, curs, colx, E);

    const dim3 ggrid((Nn + 127) / 128, HC / 128);
    const int  agrid = (Nn + 3) / 4;   // one wave per node

    // ---- layer 1 ----
    gemm_mfma_kernel<<<ggrid, 256, 0, stream>>>(x, wt1hi, wt1lo, bufA, Nn, K1);
    alpha_kernel<<<agrid, 256, 0, stream>>>(bufA, a_src1, a_dst1, as_b, ad_b, xWb, Nn);
    agg_kernel<<<agrid, 256, 0, stream>>>(rowp, colx, bufA, xWb, as_b, ad_b, b1, bufB, Nn, 1);

    // ---- layer 2 ----
    gemm_mfma_kernel<<<ggrid, 256, 0, stream>>>(bufB, wt2hi, wt2lo, bufA, Nn, HC);
    alpha_kernel<<<agrid, 256, 0, stream>>>(bufA, a_src2, a_dst2, as_b, ad_b, xWb, Nn);
    agg_kernel<<<agrid, 256, 0, stream>>>(rowp, colx, bufA, xWb, as_b, ad_b, b2, out, Nn, 0);
}

// Round 8
// 352.192 us; speedup vs baseline: 15.9769x; 1.0861x over previous
//
#include <hip/hip_runtime.h>
#include <math.h>

#define HEADS 2
#define CH    128          // per-head channels
#define HC    256          // HEADS*CH
#define NEG   0.2f         // leaky_relu slope

typedef __attribute__((ext_vector_type(8))) short  bfrag8;   // 8 bf16 (4 VGPR) MFMA operand
typedef __attribute__((ext_vector_type(4))) float  f32x4;    // MFMA accumulator

// round-to-nearest-even fp32 -> bf16 (as raw u16)
__device__ inline unsigned short f2bf_rne(float x) {
    unsigned u = __float_as_uint(x);
    u += 0x7fffu + ((u >> 16) & 1u);
    return (unsigned short)(u >> 16);
}
// 2-term split: x ~= hi + lo (both bf16); residual ~2^-16 relative
__device__ inline void split2(float x, unsigned short& hi, unsigned short& lo) {
    unsigned u = __float_as_uint(x);
    unsigned r = u + 0x7fffu + ((u >> 16) & 1u);
    unsigned short h = (unsigned short)(r >> 16);
    float hf = __uint_as_float((unsigned)h << 16);
    hi = h;
    lo = f2bf_rne(x - hf);
}

// ---------------------------------------------------------------------------
// W pre-split: W[K][HC] fp32 -> Wthi/Wtlo[HC][K] bf16 (k-contiguous, transposed)
// ---------------------------------------------------------------------------
__global__ __launch_bounds__(256)
void wsplit_kernel(const float* __restrict__ W, unsigned short* __restrict__ Whi,
                   unsigned short* __restrict__ Wlo, int K) {
    const int idx = blockIdx.x * 256 + threadIdx.x;
    if (idx >= K * HC) return;
    const int k = idx >> 8;          // HC == 256
    const int n = idx & 255;
    unsigned short h, l;
    split2(W[idx], h, l);
    Whi[(size_t)n * K + k] = h;
    Wlo[(size_t)n * K + k] = l;
}

// ---------------------------------------------------------------------------
// Fused GEMM + alpha + bf16 pack:
//   acc = A @ W (split-bf16 MFMA, fp32 accumulate)
//   xWb[row] = bf16(acc)  (messages table, 512 B/row)
//   as/ad[row, head=blockIdx.y] = dot(acc_row, a_src/a_dst)  (exact fp32)
// tile 128x128, BK=32, 4 waves (2x2); block y covers exactly one head.
// ---------------------------------------------------------------------------
__global__ __launch_bounds__(256)
void gemm_fused_kernel(const float* __restrict__ A,
                       const unsigned short* __restrict__ Wthi,
                       const unsigned short* __restrict__ Wtlo,
                       const float* __restrict__ a_src,
                       const float* __restrict__ a_dst,
                       unsigned short* __restrict__ xWb,
                       float* __restrict__ as_out, float* __restrict__ ad_out,
                       int M, int K) {
    __shared__ unsigned short Ah[128][40];
    __shared__ unsigned short Al[128][40];
    __shared__ unsigned short Bh[128][40];
    __shared__ unsigned short Bl[128][40];

    const int t    = threadIdx.x;
    const int row0 = blockIdx.x * 128;
    const int col0 = blockIdx.y * 128;   // == head * 128
    const int lane = t & 63;
    const int wid  = t >> 6;
    const int wr   = wid >> 1;
    const int wc   = wid & 1;

    f32x4 acc[4][4] = {};

    const int ar  = t >> 3;
    const int ac4 = (t & 7) * 4;
    const int bcol   = t >> 1;
    const int bplane = t & 1;

    for (int kk = 0; kk < K; kk += 32) {
        #pragma unroll
        for (int rep = 0; rep < 4; ++rep) {
            const int row = ar + rep * 32;
            const int gr  = row0 + row;
            float4 v = make_float4(0.f, 0.f, 0.f, 0.f);
            if (gr < M)
                v = *reinterpret_cast<const float4*>(&A[(size_t)gr * K + kk + ac4]);
            ushort4 hv, lv;
            split2(v.x, hv.x, lv.x);
            split2(v.y, hv.y, lv.y);
            split2(v.z, hv.z, lv.z);
            split2(v.w, hv.w, lv.w);
            *reinterpret_cast<ushort4*>(&Ah[row][ac4]) = hv;
            *reinterpret_cast<ushort4*>(&Al[row][ac4]) = lv;
        }
        {
            const unsigned short* srcp =
                (bplane ? Wtlo : Wthi) + (size_t)(col0 + bcol) * K + kk;
            unsigned short (*dst)[40] = bplane ? Bl : Bh;
            #pragma unroll
            for (int q = 0; q < 4; ++q) {
                bfrag8 v = *reinterpret_cast<const bfrag8*>(srcp + q * 8);
                *reinterpret_cast<bfrag8*>(&dst[bcol][q * 8]) = v;
            }
        }
        __syncthreads();

        bfrag8 ah[4], al[4], bh[4], bl[4];
        const int ko = (lane >> 4) * 8;
        #pragma unroll
        for (int m = 0; m < 4; ++m) {
            const int row = wr * 64 + m * 16 + (lane & 15);
            ah[m] = *reinterpret_cast<const bfrag8*>(&Ah[row][ko]);
            al[m] = *reinterpret_cast<const bfrag8*>(&Al[row][ko]);
        }
        #pragma unroll
        for (int n = 0; n < 4; ++n) {
            const int col = wc * 64 + n * 16 + (lane & 15);
            bh[n] = *reinterpret_cast<const bfrag8*>(&Bh[col][ko]);
            bl[n] = *reinterpret_cast<const bfrag8*>(&Bl[col][ko]);
        }

        #pragma unroll
        for (int m = 0; m < 4; ++m)
            #pragma unroll
            for (int n = 0; n < 4; ++n) {
                acc[m][n] = __builtin_amdgcn_mfma_f32_16x16x32_bf16(al[m], bh[n], acc[m][n], 0, 0, 0);
                acc[m][n] = __builtin_amdgcn_mfma_f32_16x16x32_bf16(ah[m], bl[n], acc[m][n], 0, 0, 0);
                acc[m][n] = __builtin_amdgcn_mfma_f32_16x16x32_bf16(ah[m], bh[n], acc[m][n], 0, 0, 0);
            }
        __syncthreads();
    }

    // ---- fused epilogue ----
    // a_src/a_dst flat index == global column (head*128 + c)
    __shared__ float s_lds[2][128];
    __shared__ float d_lds[2][128];

    float asv[4], adv[4];
    #pragma unroll
    for (int n = 0; n < 4; ++n) {
        const int gc = col0 + wc * 64 + n * 16 + (lane & 15);
        asv[n] = a_src[gc];
        adv[n] = a_dst[gc];
    }

    #pragma unroll
    for (int m = 0; m < 4; ++m) {
        #pragma unroll
        for (int reg = 0; reg < 4; ++reg) {
            const int row = wr * 64 + m * 16 + (lane >> 4) * 4 + reg;
            const int gr  = row0 + row;
            // alpha partial over this lane's 4 columns
            float ps = acc[m][0][reg] * asv[0] + acc[m][1][reg] * asv[1] +
                       acc[m][2][reg] * asv[2] + acc[m][3][reg] * asv[3];
            float pd = acc[m][0][reg] * adv[0] + acc[m][1][reg] * adv[1] +
                       acc[m][2][reg] * adv[2] + acc[m][3][reg] * adv[3];
            #pragma unroll
            for (int msk = 1; msk <= 8; msk <<= 1) {
                ps += __shfl_xor(ps, msk);
                pd += __shfl_xor(pd, msk);
            }
            if ((lane & 15) == 0) {
                s_lds[wc][row] = ps;
                d_lds[wc][row] = pd;
            }
            // bf16 message store
            if (gr < M) {
                unsigned short* rp = &xWb[(size_t)gr * HC + col0];
                #pragma unroll
                for (int n = 0; n < 4; ++n)
                    rp[wc * 64 + n * 16 + (lane & 15)] = f2bf_rne(acc[m][n][reg]);
            }
        }
    }
    __syncthreads();
    if (t < 128) {
        const int gr = row0 + t;
        if (gr < M) {
            as_out[gr * 2 + blockIdx.y] = s_lds[0][t] + s_lds[1][t];
            ad_out[gr * 2 + blockIdx.y] = d_lds[0][t] + d_lds[1][t];
        }
    }
}

// ---------------------------------------------------------------------------
// CSR build: histogram -> 2-level exclusive scan -> scatter (by destination)
// ---------------------------------------------------------------------------
__global__ __launch_bounds__(256)
void hist_kernel(const int* __restrict__ dst, int* __restrict__ counts, int E) {
    const int e = blockIdx.x * 256 + threadIdx.x;
    if (e < E) atomicAdd(&counts[dst[e]], 1);
}

__global__ __launch_bounds__(256)
void scan_local_kernel(int* __restrict__ data, int* __restrict__ chunk_sum, int N) {
    __shared__ int s[256];
    const int t   = threadIdx.x;
    const int idx = blockIdx.x * 256 + t;
    const int v   = (idx < N) ? data[idx] : 0;
    s[t] = v;
    __syncthreads();
    #pragma unroll
    for (int off = 1; off < 256; off <<= 1) {
        int x = (t >= off) ? s[t - off] : 0;
        __syncthreads();
        s[t] += x;
        __syncthreads();
    }
    if (idx < N) data[idx] = s[t] - v;        // exclusive
    if (t == 255) chunk_sum[blockIdx.x] = s[255];
}

__global__ __launch_bounds__(256)
void scan_chunks_kernel(int* __restrict__ chunk, int nb) {
    __shared__ int s[256];
    const int t = threadIdx.x;
    const int v = (t < nb) ? chunk[t] : 0;
    s[t] = v;
    __syncthreads();
    #pragma unroll
    for (int off = 1; off < 256; off <<= 1) {
        int x = (t >= off) ? s[t - off] : 0;
        __syncthreads();
        s[t] += x;
        __syncthreads();
    }
    if (t < nb) chunk[t] = s[t] - v;
}

__global__ __launch_bounds__(256)
void add_offsets_kernel(const int* __restrict__ excl, const int* __restrict__ chunk_excl,
                        int* __restrict__ row_ptr, int* __restrict__ cursor,
                        int N, int E) {
    const int idx = blockIdx.x * 256 + threadIdx.x;
    if (idx < N) {
        const int rp = excl[idx] + chunk_excl[idx >> 8];
        row_ptr[idx] = rp;
        cursor[idx]  = rp;
    }
    if (idx == 0) row_ptr[N] = E;
}

__global__ __launch_bounds__(256)
void scatter_kernel(const int* __restrict__ src, const int* __restrict__ dst,
                    int* __restrict__ cursor, int* __restrict__ col_idx, int E) {
    const int e = blockIdx.x * 256 + threadIdx.x;
    if (e < E) {
        const int pos = atomicAdd(&cursor[dst[e]], 1);
        col_idx[pos] = src[e];
    }
}

// ---------------------------------------------------------------------------
// gather aggregation + fused epilogue: one wave per target node.
// bf16 messages AND bf16 self-loop; 2 edges in flight (lanes 0-31 / 32-63).
// sublane sl=lane&31 covers 8 channels: cb = (sl>>4)*128 + (sl&15)*8
// ---------------------------------------------------------------------------
__global__ __launch_bounds__(256)
void agg_kernel(const int* __restrict__ row_ptr, const int* __restrict__ col_idx,
                const unsigned short* __restrict__ xWb,
                const float* __restrict__ as_, const float* __restrict__ ad_,
                const float* __restrict__ bias, float* __restrict__ out,
                int N, int do_elu) {
    const int wv   = (blockIdx.x * 256 + threadIdx.x) >> 6;
    const int lane = threadIdx.x & 63;
    if (wv >= N) return;
    const int i    = wv;
    const int half = lane >> 5;          // which edge stream
    const int sl   = lane & 31;
    const int hh   = sl >> 4;            // head of this sublane
    const int cb   = hh * 128 + (sl & 15) * 8;   // 8-channel block base
    const float adi = ad_[i * 2 + hh];

    float acc[8] = {};
    float dn = 0.f;

    const int beg = row_ptr[i];
    const int end = row_ptr[i + 1];

    int k = beg + half;
    int j = (k < end) ? col_idx[k] : 0;
    for (; k < end; k += 2) {
        const int jn = (k + 2 < end) ? col_idx[k + 2] : 0;   // prefetch
        float e = as_[j * 2 + hh] + adi;
        e = e > 0.f ? e : NEG * e;
        const float w = expf(e);
        const uint4 q = *reinterpret_cast<const uint4*>(&xWb[(size_t)j * HC + cb]);
        const unsigned qq[4] = {q.x, q.y, q.z, q.w};
        #pragma unroll
        for (int r = 0; r < 4; ++r) {
            const float flo = __uint_as_float(qq[r] << 16);
            const float fhi = __uint_as_float(qq[r] & 0xffff0000u);
            acc[r * 2 + 0] = fmaf(w, flo, acc[r * 2 + 0]);
            acc[r * 2 + 1] = fmaf(w, fhi, acc[r * 2 + 1]);
        }
        dn += w;
        j = jn;
    }

    // merge the two edge streams
    #pragma unroll
    for (int r = 0; r < 8; ++r) acc[r] += __shfl_xor(acc[r], 32);
    dn += __shfl_xor(dn, 32);

    if (lane < 32) {
        // self loop (bf16 row — same error class as neighbor messages)
        float e = as_[i * 2 + hh] + adi;
        e = e > 0.f ? e : NEG * e;
        const float ws = expf(e);
        const uint4 q = *reinterpret_cast<const uint4*>(&xWb[(size_t)i * HC + cb]);
        const unsigned qq[4] = {q.x, q.y, q.z, q.w};
        #pragma unroll
        for (int r = 0; r < 4; ++r) {
            const float flo = __uint_as_float(qq[r] << 16);
            const float fhi = __uint_as_float(qq[r] & 0xffff0000u);
            acc[r * 2 + 0] = fmaf(ws, flo, acc[r * 2 + 0]);
            acc[r * 2 + 1] = fmaf(ws, fhi, acc[r * 2 + 1]);
        }
        dn += ws;

        const float inv = 1.f / dn;
        const float4 b0 = *reinterpret_cast<const float4*>(&bias[cb]);
        const float4 b1 = *reinterpret_cast<const float4*>(&bias[cb + 4]);
        float o[8];
        o[0] = acc[0] * inv + b0.x; o[1] = acc[1] * inv + b0.y;
        o[2] = acc[2] * inv + b0.z; o[3] = acc[3] * inv + b0.w;
        o[4] = acc[4] * inv + b1.x; o[5] = acc[5] * inv + b1.y;
        o[6] = acc[6] * inv + b1.z; o[7] = acc[7] * inv + b1.w;
        if (do_elu) {
            #pragma unroll
            for (int r = 0; r < 8; ++r) o[r] = o[r] > 0.f ? o[r] : expm1f(o[r]);
        }
        *reinterpret_cast<float4*>(&out[(size_t)i * HC + cb]) =
            make_float4(o[0], o[1], o[2], o[3]);
        *reinterpret_cast<float4*>(&out[(size_t)i * HC + cb + 4]) =
            make_float4(o[4], o[5], o[6], o[7]);
    }
}

// ---------------------------------------------------------------------------
extern "C" void kernel_launch(void* const* d_in, const int* in_sizes, int n_in,
                              void* d_out, int out_size, void* d_ws, size_t ws_size,
                              hipStream_t stream) {
    const float* x      = (const float*)d_in[0];
    const int*   ei     = (const int*)d_in[1];
    const float* W1     = (const float*)d_in[2];
    const float* a_src1 = (const float*)d_in[3];
    const float* a_dst1 = (const float*)d_in[4];
    const float* b1     = (const float*)d_in[5];
    const float* W2     = (const float*)d_in[6];
    const float* a_src2 = (const float*)d_in[7];
    const float* a_dst2 = (const float*)d_in[8];
    const float* b2     = (const float*)d_in[9];
    float* out = (float*)d_out;

    const int Nn = in_sizes[0] / 128;   // 50000 nodes
    const int E  = in_sizes[1] / 2;     // 800000 edges
    const int K1 = in_sizes[2] / HC;    // 128
    const int* src = ei;
    const int* dst = ei + E;

    // workspace layout
    float* bufB  = (float*)d_ws;                  // Nn*HC  (h, fp32)
    float* as_b  = bufB + (size_t)Nn * HC;        // Nn*2
    float* ad_b  = as_b + (size_t)Nn * 2;         // Nn*2
    int*   tmp   = (int*)(ad_b + (size_t)Nn * 2); // Nn  (counts -> excl scan)
    int*   chunk = tmp + Nn;                      // 256
    int*   rowp  = chunk + 256;                   // Nn+1
    int*   curs  = rowp + (Nn + 1);               // Nn
    int*   colx  = curs + Nn;                     // E
    unsigned short* wt1hi = (unsigned short*)(colx + E);   // HC*K1
    unsigned short* wt1lo = wt1hi + (size_t)HC * K1;
    unsigned short* wt2hi = wt1lo + (size_t)HC * K1;       // HC*HC
    unsigned short* wt2lo = wt2hi + (size_t)HC * HC;
    unsigned short* xWb   = wt2lo + (size_t)HC * HC;       // Nn*HC bf16 messages

    const int nb = (Nn + 255) / 256;

    // ---- W pre-split (tiny) ----
    wsplit_kernel<<<(K1 * HC + 255) / 256, 256, 0, stream>>>(W1, wt1hi, wt1lo, K1);
    wsplit_kernel<<<(HC * HC + 255) / 256, 256, 0, stream>>>(W2, wt2hi, wt2lo, HC);

    // ---- CSR build (shared by both layers) ----
    hipMemsetAsync(tmp, 0, (size_t)Nn * sizeof(int), stream);
    hist_kernel<<<(E + 255) / 256, 256, 0, stream>>>(dst, tmp, E);
    scan_local_kernel<<<nb, 256, 0, stream>>>(tmp, chunk, Nn);
    scan_chunks_kernel<<<1, 256, 0, stream>>>(chunk, nb);
    add_offsets_kernel<<<nb, 256, 0, stream>>>(tmp, chunk, rowp, curs, Nn, E);
    scatter_kernel<<<(E + 255) / 256, 256, 0, stream>>>(src, dst, curs, colx, E);

    const dim3 ggrid((Nn + 127) / 128, HC / 128);
    const int  agrid = (Nn + 3) / 4;   // one wave per node

    // ---- layer 1 ----
    gemm_fused_kernel<<<ggrid, 256, 0, stream>>>(x, wt1hi, wt1lo, a_src1, a_dst1,
                                                 xWb, as_b, ad_b, Nn, K1);
    agg_kernel<<<agrid, 256, 0, stream>>>(rowp, colx, xWb, as_b, ad_b, b1, bufB, Nn, 1);

    // ---- layer 2 ----
    gemm_fused_kernel<<<ggrid, 256, 0, stream>>>(bufB, wt2hi, wt2lo, a_src2, a_dst2,
                                                 xWb, as_b, ad_b, Nn, HC);
    agg_kernel<<<agrid, 256, 0, stream>>>(rowp, colx, xWb, as_b, ad_b, b2, out, Nn, 0);
}